// Round 7
// baseline (268.855 us; speedup 1.0000x reference)
//
#include <hip/hip_runtime.h>
#include <stdint.h>

#define DIMC 1024
#define NSEQ 4096
#define NH 16
#define QSCALE 0.18033688011112042f   // 0.125 * log2(e): scores come out in exp2 domain

typedef __attribute__((ext_vector_type(8))) short bf16x8;
typedef __attribute__((ext_vector_type(4))) float f32x4;

__device__ __forceinline__ unsigned short f2bf(float x) {
    union { float f; unsigned int u; } v; v.f = x;
    unsigned int u = v.u;
    return (unsigned short)((u + 0x7fffu + ((u >> 16) & 1u)) >> 16);
}

__device__ __forceinline__ unsigned cvt_pk_bf16(float lo, float hi) {
    unsigned r;
    asm("v_cvt_pk_bf16_f32 %0, %1, %2" : "=v"(r) : "v"(lo), "v"(hi));
    return r;
}

__device__ __forceinline__ void gload16(const unsigned short* g, unsigned short* l) {
    __builtin_amdgcn_global_load_lds(
        (const __attribute__((address_space(1))) void*)g,
        (__attribute__((address_space(3))) void*)l, 16, 0, 0);
}

// ---- content fp32 -> bf16 ----
__global__ __launch_bounds__(256) void k_conv(const float* __restrict__ in,
                                              unsigned short* __restrict__ out) {
    int i = (blockIdx.x * 256 + threadIdx.x) * 8;
    float4 a = *reinterpret_cast<const float4*>(in + i);
    float4 b = *reinterpret_cast<const float4*>(in + i + 4);
    union { unsigned short us[8]; uint4 v; } r;
    r.us[0] = f2bf(a.x); r.us[1] = f2bf(a.y); r.us[2] = f2bf(a.z); r.us[3] = f2bf(a.w);
    r.us[4] = f2bf(b.x); r.us[5] = f2bf(b.y); r.us[6] = f2bf(b.z); r.us[7] = f2bf(b.w);
    *reinterpret_cast<uint4*>(out + i) = r.v;
}

// ---- W fp32 -> bf16, transposed (Wt[n][k] = W[k][n]) ----
__global__ __launch_bounds__(1024) void k_wt(const float* __restrict__ Wq,
                                             const float* __restrict__ Wk,
                                             const float* __restrict__ Wv,
                                             unsigned short* __restrict__ wt) {
    __shared__ float tile[32][33];
    int z = blockIdx.z;
    const float* W = (z == 0) ? Wq : ((z == 1) ? Wk : Wv);
    int n0 = blockIdx.x * 32, k0 = blockIdx.y * 32;
    tile[threadIdx.y][threadIdx.x] = W[(k0 + threadIdx.y) * DIMC + n0 + threadIdx.x];
    __syncthreads();
    wt[(size_t)z * DIMC * DIMC + (n0 + threadIdx.y) * DIMC + k0 + threadIdx.x] =
        f2bf(tile[threadIdx.x][threadIdx.y]);
}

// ---- QKV GEMM (m97 structure: global_load_lds w16, linear LDS) ----
__global__ __launch_bounds__(256) void k_gemm(const unsigned short* __restrict__ A,
                                              const unsigned short* __restrict__ Wt,
                                              unsigned short* __restrict__ Qb,
                                              unsigned short* __restrict__ Kb,
                                              unsigned short* __restrict__ Vt) {
    __shared__ unsigned short As[128 * 32];
    __shared__ unsigned short Bs[128 * 32];
    const int z = blockIdx.z;
    const unsigned short* Wz = Wt + (size_t)z * DIMC * DIMC;
    const int n0 = blockIdx.x * 128, m0 = blockIdx.y * 128;
    const int t = threadIdx.x;
    const int w = t >> 6, l = t & 63;
    const int wr = w >> 1, wc = w & 1;
    const int lq = l & 15, lg = l >> 4;
    const int srow = l >> 2, scol = (l & 3) * 8;
    const unsigned short* gA = A  + (size_t)(m0 + w * 32 + srow) * DIMC + scol;
    const unsigned short* gB = Wz + (size_t)(n0 + w * 32 + srow) * DIMC + scol;
    unsigned short* lA = &As[(2 * w) * 512];
    unsigned short* lB = &Bs[(2 * w) * 512];

    f32x4 acc[4][4];
    #pragma unroll
    for (int i = 0; i < 4; ++i)
        #pragma unroll
        for (int j = 0; j < 4; ++j)
            acc[i][j] = f32x4{0.f, 0.f, 0.f, 0.f};

    for (int k0 = 0; k0 < DIMC; k0 += 32) {
        __syncthreads();
        gload16(gA + k0, lA);
        gload16(gA + k0 + 16 * DIMC, lA + 512);
        gload16(gB + k0, lB);
        gload16(gB + k0 + 16 * DIMC, lB + 512);
        __syncthreads();
        bf16x8 af[4], bfr[4];
        #pragma unroll
        for (int mf = 0; mf < 4; ++mf)
            af[mf] = *reinterpret_cast<const bf16x8*>(&As[(wr * 64 + mf * 16 + lq) * 32 + lg * 8]);
        #pragma unroll
        for (int nf = 0; nf < 4; ++nf)
            bfr[nf] = *reinterpret_cast<const bf16x8*>(&Bs[(wc * 64 + nf * 16 + lq) * 32 + lg * 8]);
        __builtin_amdgcn_s_setprio(1);
        #pragma unroll
        for (int mf = 0; mf < 4; ++mf)
            #pragma unroll
            for (int nf = 0; nf < 4; ++nf)
                acc[mf][nf] = __builtin_amdgcn_mfma_f32_16x16x32_bf16(af[mf], bfr[nf], acc[mf][nf], 0, 0, 0);
        __builtin_amdgcn_s_setprio(0);
    }

    if (z < 2) {
        unsigned short* out = (z == 0) ? Qb : Kb;
        const float osc = (z == 0) ? QSCALE : 1.0f;
        #pragma unroll
        for (int mf = 0; mf < 4; ++mf)
            #pragma unroll
            for (int nf = 0; nf < 4; ++nf)
                #pragma unroll
                for (int j = 0; j < 4; ++j) {
                    int row = m0 + wr * 64 + mf * 16 + lg * 4 + j;
                    int col = n0 + wc * 64 + nf * 16 + lq;
                    out[row * DIMC + col] = f2bf(acc[mf][nf][j] * osc);
                }
    } else {
        #pragma unroll
        for (int mf = 0; mf < 4; ++mf)
            #pragma unroll
            for (int nf = 0; nf < 4; ++nf) {
                int row  = n0 + wc * 64 + nf * 16 + lq;       // d index
                int colb = m0 + wr * 64 + mf * 16 + lg * 4;   // seq index
                uint2 pk;
                pk.x = cvt_pk_bf16(acc[mf][nf][0], acc[mf][nf][1]);
                pk.y = cvt_pk_bf16(acc[mf][nf][2], acc[mf][nf][3]);
                *reinterpret_cast<uint2*>(Vt + (size_t)row * NSEQ + colb) = pk;
            }
    }
}

// ---- fused attention: 4 waves x 32q, paired 64-row halves, dbuf K/V, 1 barrier/tile ----
__global__ __launch_bounds__(256) void k_attn(const unsigned short* __restrict__ Qb,
                                              const unsigned short* __restrict__ Kb,
                                              const unsigned short* __restrict__ Vt,
                                              float* __restrict__ Y) {
    __shared__ unsigned short Ks[2][64][72];   // [buf][k][d]
    __shared__ unsigned short Vs[2][64][72];   // [buf][d][k]
    __shared__ unsigned short Ps[4][32][72];   // per-wave P bounce [wave][q][k]
    // XCD-aware decode: 2 heads per XCD; all blocks of a head share one L2
    const int bid = blockIdx.x;
    const int x = bid & 7, i = bid >> 3;
    const int h = x * 2 + (i >> 5);
    const int bx = i & 31;
    const int t = threadIdx.x;
    const int w = t >> 6, l = t & 63;
    const int half = w >> 1, wq = w & 1;       // 4 waves = 2 halves x 2 row-groups
    const int lq = l & 15, lg = l >> 4;
    const int qbA = bx, qbB = 63 - bx;         // 64-row tiles; per-block PV uniform
    const int qb_my = half ? qbB : qbA;
    const int vmax = qbB;                      // last kt needing V staged
    const int pvmax = qb_my;                   // last kt with PV work (diag tile)

    // Q frags (pre-scaled): rows qb_my*64 + wq*32 + g*16 + lq
    bf16x8 qf[2][2];
    #pragma unroll
    for (int g = 0; g < 2; ++g) {
        const unsigned short* qp = Qb + (size_t)(qb_my * 64 + wq * 32 + g * 16 + lq) * DIMC + h * 64 + lg * 8;
        qf[g][0] = *reinterpret_cast<const bf16x8*>(qp);
        qf[g][1] = *reinterpret_cast<const bf16x8*>(qp + 32);
    }
    float m_fr[2] = {-__builtin_inff(), -__builtin_inff()};
    float l_st[2] = {0.f, 0.f};
    f32x4 O[2][4];
    #pragma unroll
    for (int g = 0; g < 2; ++g)
        #pragma unroll
        for (int df = 0; df < 4; ++df) O[g][df] = f32x4{0.f, 0.f, 0.f, 0.f};

    // staging: 256 threads, each covers rows r0 and r0+32 of the 64x64 tile
    const int r0 = t >> 3, c0 = (t & 7) * 8;
    const unsigned short* gK = Kb + (size_t)r0 * DIMC + h * 64 + c0;
    const unsigned short* gV = Vt + (size_t)(h * 64 + r0) * NSEQ + c0;

    // prologue: tile 0 direct to buf0; prefetch tile 1 into regs
    *reinterpret_cast<uint4*>(&Ks[0][r0][c0])      = *reinterpret_cast<const uint4*>(gK);
    *reinterpret_cast<uint4*>(&Ks[0][r0 + 32][c0]) = *reinterpret_cast<const uint4*>(gK + 32 * DIMC);
    *reinterpret_cast<uint4*>(&Vs[0][r0][c0])      = *reinterpret_cast<const uint4*>(gV);
    *reinterpret_cast<uint4*>(&Vs[0][r0 + 32][c0]) = *reinterpret_cast<const uint4*>(gV + 32 * NSEQ);
    uint4 kv0 = *reinterpret_cast<const uint4*>(gK + 64 * DIMC);
    uint4 kv1 = *reinterpret_cast<const uint4*>(gK + 96 * DIMC);
    uint4 vv0 = *reinterpret_cast<const uint4*>(gV + 64);
    uint4 vv1 = *reinterpret_cast<const uint4*>(gV + 32 * NSEQ + 64);

    for (int kt = 0; kt < 64; ++kt) {
        const int cur = kt & 1, nxt = cur ^ 1;
        __syncthreads();   // single barrier: prev iter's reads done -> safe to overwrite nxt
        if (kt + 1 < 64) {
            *reinterpret_cast<uint4*>(&Ks[nxt][r0][c0])      = kv0;
            *reinterpret_cast<uint4*>(&Ks[nxt][r0 + 32][c0]) = kv1;
            if (kt + 1 <= vmax) {
                *reinterpret_cast<uint4*>(&Vs[nxt][r0][c0])      = vv0;
                *reinterpret_cast<uint4*>(&Vs[nxt][r0 + 32][c0]) = vv1;
            }
        }
        if (kt + 2 < 64) {   // prefetch tile kt+2 (2 tiles of latency cover)
            kv0 = *reinterpret_cast<const uint4*>(gK + (size_t)(kt + 2) * 64 * DIMC);
            kv1 = *reinterpret_cast<const uint4*>(gK + (size_t)(kt + 2) * 64 * DIMC + 32 * DIMC);
            if (kt + 2 <= vmax) {
                vv0 = *reinterpret_cast<const uint4*>(gV + (kt + 2) * 64);
                vv1 = *reinterpret_cast<const uint4*>(gV + 32 * NSEQ + (kt + 2) * 64);
            }
        }

        // swapped QK^T, both q-groups share K frags: s[g] holds S^T[k][q] (exp2 domain)
        f32x4 s[2][4];
        #pragma unroll
        for (int g = 0; g < 2; ++g)
            #pragma unroll
            for (int f = 0; f < 4; ++f) s[g][f] = f32x4{0.f, 0.f, 0.f, 0.f};
        __builtin_amdgcn_s_setprio(1);
        #pragma unroll
        for (int f = 0; f < 4; ++f) {
            bf16x8 ka0 = *reinterpret_cast<const bf16x8*>(&Ks[cur][f * 16 + lq][lg * 8]);
            bf16x8 ka1 = *reinterpret_cast<const bf16x8*>(&Ks[cur][f * 16 + lq][32 + lg * 8]);
            s[0][f] = __builtin_amdgcn_mfma_f32_16x16x32_bf16(ka0, qf[0][0], s[0][f], 0, 0, 0);
            s[0][f] = __builtin_amdgcn_mfma_f32_16x16x32_bf16(ka1, qf[0][1], s[0][f], 0, 0, 0);
            s[1][f] = __builtin_amdgcn_mfma_f32_16x16x32_bf16(ka0, qf[1][0], s[1][f], 0, 0, 0);
            s[1][f] = __builtin_amdgcn_mfma_f32_16x16x32_bf16(ka1, qf[1][1], s[1][f], 0, 0, 0);
        }
        __builtin_amdgcn_s_setprio(0);

        // lane-local frame check (no cross-lane max in the common path)
        float tl[2];
        #pragma unroll
        for (int g = 0; g < 2; ++g) {
            float m = s[g][0][0];
            #pragma unroll
            for (int f = 0; f < 4; ++f)
                #pragma unroll
                for (int j = 0; j < 4; ++j) m = fmaxf(m, s[g][f][j]);
            tl[g] = m;
        }
        if (!__all((tl[0] <= m_fr[0] + 8.f) && (tl[1] <= m_fr[1] + 8.f))) {
            #pragma unroll
            for (int g = 0; g < 2; ++g) {
                float tm = tl[g];
                tm = fmaxf(tm, __shfl_xor(tm, 16));
                tm = fmaxf(tm, __shfl_xor(tm, 32));
                const float mnew = fmaxf(m_fr[g], tm);
                const float sc = exp2f(m_fr[g] - mnew);   // first tile: 0
                l_st[g] *= sc;
                #pragma unroll
                for (int j = 0; j < 4; ++j) {
                    const float scj = __shfl(sc, lg * 4 + j);
                    #pragma unroll
                    for (int df = 0; df < 4; ++df) O[g][df][j] *= scj;
                }
                m_fr[g] = mnew;
            }
        }
        // exp2 + denominator (UNMASKED: full-row softmax denominator)
        #pragma unroll
        for (int g = 0; g < 2; ++g) {
            float ps = 0.f;
            #pragma unroll
            for (int f = 0; f < 4; ++f)
                #pragma unroll
                for (int j = 0; j < 4; ++j) {
                    const float p = exp2f(s[g][f][j] - m_fr[g]);
                    s[g][f][j] = p;
                    ps += p;
                }
            ps += __shfl_xor(ps, 16);
            ps += __shfl_xor(ps, 32);
            l_st[g] += ps;
        }

        if (kt <= pvmax) {
            if (kt == pvmax) {   // diagonal tile: post-softmax tril mask
                #pragma unroll
                for (int g = 0; g < 2; ++g) {
                    const int qrel = wq * 32 + g * 16 + lq;
                    #pragma unroll
                    for (int f = 0; f < 4; ++f) {
                        const int kbase = f * 16 + lg * 4;
                        #pragma unroll
                        for (int j = 0; j < 4; ++j)
                            if (kbase + j > qrel) s[g][f][j] = 0.f;
                    }
                }
            }
            #pragma unroll
            for (int g = 0; g < 2; ++g)
                #pragma unroll
                for (int f = 0; f < 4; ++f) {
                    uint2 pk;
                    pk.x = cvt_pk_bf16(s[g][f][0], s[g][f][1]);
                    pk.y = cvt_pk_bf16(s[g][f][2], s[g][f][3]);
                    *reinterpret_cast<uint2*>(&Ps[w][g * 16 + lq][f * 16 + lg * 4]) = pk;
                }
            __builtin_amdgcn_s_setprio(1);
            #pragma unroll
            for (int kk = 0; kk < 2; ++kk) {
                bf16x8 pa0 = *reinterpret_cast<const bf16x8*>(&Ps[w][lq][kk * 32 + lg * 8]);
                bf16x8 pa1 = *reinterpret_cast<const bf16x8*>(&Ps[w][16 + lq][kk * 32 + lg * 8]);
                #pragma unroll
                for (int df = 0; df < 4; ++df) {
                    bf16x8 vb = *reinterpret_cast<const bf16x8*>(&Vs[cur][df * 16 + lq][kk * 32 + lg * 8]);
                    O[0][df] = __builtin_amdgcn_mfma_f32_16x16x32_bf16(pa0, vb, O[0][df], 0, 0, 0);
                    O[1][df] = __builtin_amdgcn_mfma_f32_16x16x32_bf16(pa1, vb, O[1][df], 0, 0, 0);
                }
            }
            __builtin_amdgcn_s_setprio(0);
        }
    }

    // epilogue: O and l share frame m_fr[g]
    #pragma unroll
    for (int g = 0; g < 2; ++g) {
        const float rl = 1.0f / l_st[g];
        #pragma unroll
        for (int j = 0; j < 4; ++j) {
            const float li = __shfl(rl, lg * 4 + j);
            #pragma unroll
            for (int df = 0; df < 4; ++df)
                Y[(size_t)(qb_my * 64 + wq * 32 + g * 16 + lg * 4 + j) * DIMC + h * 64 + df * 16 + lq] = O[g][df][j] * li;
        }
    }
}

extern "C" void kernel_launch(void* const* d_in, const int* in_sizes, int n_in,
                              void* d_out, int out_size, void* d_ws, size_t ws_size,
                              hipStream_t stream) {
    const float* content = (const float*)d_in[0];
    const float* Wq = (const float*)d_in[1];
    const float* Wk = (const float*)d_in[2];
    const float* Wv = (const float*)d_in[3];
    float* Y = (float*)d_out;
    unsigned short* ws  = (unsigned short*)d_ws;
    unsigned short* cbf = ws;
    unsigned short* wt  = cbf + (size_t)NSEQ * DIMC;
    unsigned short* qb  = wt  + (size_t)3 * DIMC * DIMC;
    unsigned short* kb  = qb  + (size_t)NSEQ * DIMC;
    unsigned short* vt  = kb  + (size_t)NSEQ * DIMC;

    hipLaunchKernelGGL(k_conv, dim3(NSEQ * DIMC / (256 * 8)), dim3(256), 0, stream, content, cbf);
    hipLaunchKernelGGL(k_wt,   dim3(32, 32, 3), dim3(32, 32), 0, stream, Wq, Wk, Wv, wt);
    hipLaunchKernelGGL(k_gemm, dim3(DIMC / 128, NSEQ / 128, 3), dim3(256), 0, stream, cbf, wt, qb, kb, vt);
    hipLaunchKernelGGL(k_attn, dim3(512), dim3(256), 0, stream, qb, kb, vt, Y);
}

// Round 8
// 261.703 us; speedup vs baseline: 1.0273x; 1.0273x over previous
//
#include <hip/hip_runtime.h>
#include <stdint.h>

#define DIMC 1024
#define NSEQ 4096
#define NH 16
#define QSCALE 0.18033688011112042f   // 0.125 * log2(e): scores come out in exp2 domain

typedef __attribute__((ext_vector_type(8))) short bf16x8;
typedef __attribute__((ext_vector_type(4))) float f32x4;
typedef __attribute__((ext_vector_type(16))) float f32x16;

__device__ __forceinline__ unsigned short f2bf(float x) {
    union { float f; unsigned int u; } v; v.f = x;
    unsigned int u = v.u;
    return (unsigned short)((u + 0x7fffu + ((u >> 16) & 1u)) >> 16);
}

__device__ __forceinline__ unsigned cvt_pk_bf16(float lo, float hi) {
    unsigned r;
    asm("v_cvt_pk_bf16_f32 %0, %1, %2" : "=v"(r) : "v"(lo), "v"(hi));
    return r;
}

__device__ __forceinline__ void gload16(const unsigned short* g, unsigned short* l) {
    __builtin_amdgcn_global_load_lds(
        (const __attribute__((address_space(1))) void*)g,
        (__attribute__((address_space(3))) void*)l, 16, 0, 0);
}

// ---- content fp32 -> bf16 ----
__global__ __launch_bounds__(256) void k_conv(const float* __restrict__ in,
                                              unsigned short* __restrict__ out) {
    int i = (blockIdx.x * 256 + threadIdx.x) * 8;
    float4 a = *reinterpret_cast<const float4*>(in + i);
    float4 b = *reinterpret_cast<const float4*>(in + i + 4);
    union { unsigned short us[8]; uint4 v; } r;
    r.us[0] = f2bf(a.x); r.us[1] = f2bf(a.y); r.us[2] = f2bf(a.z); r.us[3] = f2bf(a.w);
    r.us[4] = f2bf(b.x); r.us[5] = f2bf(b.y); r.us[6] = f2bf(b.z); r.us[7] = f2bf(b.w);
    *reinterpret_cast<uint4*>(out + i) = r.v;
}

// ---- W fp32 -> bf16, transposed (Wt[n][k] = W[k][n]) ----
__global__ __launch_bounds__(1024) void k_wt(const float* __restrict__ Wq,
                                             const float* __restrict__ Wk,
                                             const float* __restrict__ Wv,
                                             unsigned short* __restrict__ wt) {
    __shared__ float tile[32][33];
    int z = blockIdx.z;
    const float* W = (z == 0) ? Wq : ((z == 1) ? Wk : Wv);
    int n0 = blockIdx.x * 32, k0 = blockIdx.y * 32;
    tile[threadIdx.y][threadIdx.x] = W[(k0 + threadIdx.y) * DIMC + n0 + threadIdx.x];
    __syncthreads();
    wt[(size_t)z * DIMC * DIMC + (n0 + threadIdx.y) * DIMC + k0 + threadIdx.x] =
        f2bf(tile[threadIdx.x][threadIdx.y]);
}

// ---- QKV GEMM (m97 structure: global_load_lds w16, linear LDS) ----
__global__ __launch_bounds__(256) void k_gemm(const unsigned short* __restrict__ A,
                                              const unsigned short* __restrict__ Wt,
                                              unsigned short* __restrict__ Qb,
                                              unsigned short* __restrict__ Kb,
                                              unsigned short* __restrict__ Vt) {
    __shared__ unsigned short As[128 * 32];
    __shared__ unsigned short Bs[128 * 32];
    const int z = blockIdx.z;
    const unsigned short* Wz = Wt + (size_t)z * DIMC * DIMC;
    const int n0 = blockIdx.x * 128, m0 = blockIdx.y * 128;
    const int t = threadIdx.x;
    const int w = t >> 6, l = t & 63;
    const int wr = w >> 1, wc = w & 1;
    const int lq = l & 15, lg = l >> 4;
    const int srow = l >> 2, scol = (l & 3) * 8;
    const unsigned short* gA = A  + (size_t)(m0 + w * 32 + srow) * DIMC + scol;
    const unsigned short* gB = Wz + (size_t)(n0 + w * 32 + srow) * DIMC + scol;
    unsigned short* lA = &As[(2 * w) * 512];
    unsigned short* lB = &Bs[(2 * w) * 512];

    f32x4 acc[4][4];
    #pragma unroll
    for (int i = 0; i < 4; ++i)
        #pragma unroll
        for (int j = 0; j < 4; ++j)
            acc[i][j] = f32x4{0.f, 0.f, 0.f, 0.f};

    for (int k0 = 0; k0 < DIMC; k0 += 32) {
        __syncthreads();
        gload16(gA + k0, lA);
        gload16(gA + k0 + 16 * DIMC, lA + 512);
        gload16(gB + k0, lB);
        gload16(gB + k0 + 16 * DIMC, lB + 512);
        __syncthreads();
        bf16x8 af[4], bfr[4];
        #pragma unroll
        for (int mf = 0; mf < 4; ++mf)
            af[mf] = *reinterpret_cast<const bf16x8*>(&As[(wr * 64 + mf * 16 + lq) * 32 + lg * 8]);
        #pragma unroll
        for (int nf = 0; nf < 4; ++nf)
            bfr[nf] = *reinterpret_cast<const bf16x8*>(&Bs[(wc * 64 + nf * 16 + lq) * 32 + lg * 8]);
        __builtin_amdgcn_s_setprio(1);
        #pragma unroll
        for (int mf = 0; mf < 4; ++mf)
            #pragma unroll
            for (int nf = 0; nf < 4; ++nf)
                acc[mf][nf] = __builtin_amdgcn_mfma_f32_16x16x32_bf16(af[mf], bfr[nf], acc[mf][nf], 0, 0, 0);
        __builtin_amdgcn_s_setprio(0);
    }

    if (z < 2) {
        unsigned short* out = (z == 0) ? Qb : Kb;
        const float osc = (z == 0) ? QSCALE : 1.0f;
        #pragma unroll
        for (int mf = 0; mf < 4; ++mf)
            #pragma unroll
            for (int nf = 0; nf < 4; ++nf)
                #pragma unroll
                for (int j = 0; j < 4; ++j) {
                    int row = m0 + wr * 64 + mf * 16 + lg * 4 + j;
                    int col = n0 + wc * 64 + nf * 16 + lq;
                    out[row * DIMC + col] = f2bf(acc[mf][nf][j] * osc);
                }
    } else {
        #pragma unroll
        for (int mf = 0; mf < 4; ++mf)
            #pragma unroll
            for (int nf = 0; nf < 4; ++nf) {
                int row  = n0 + wc * 64 + nf * 16 + lq;       // d index
                int colb = m0 + wr * 64 + mf * 16 + lg * 4;   // seq index
                uint2 pk;
                pk.x = cvt_pk_bf16(acc[mf][nf][0], acc[mf][nf][1]);
                pk.y = cvt_pk_bf16(acc[mf][nf][2], acc[mf][nf][3]);
                *reinterpret_cast<uint2*>(Vt + (size_t)row * NSEQ + colb) = pk;
            }
    }
}

// swizzled LDS index: row stride 64 elems (128 B, b128-aligned), col ^= (row&7)*8
// -> each b128 wave-read spreads uniformly over all 8 16B-slots (optimal for b128)
#define KIDX(r, c) ((r) * 64 + ((c) ^ (((r) & 7) * 8)))

// P-transpose + PV step for one K=16 slice. SF = S^T frag (f32x16), s16 = slice
// within frag, kk = global 16-slice in [0,4). Derivation: S^T C-layout row
// k = (reg&3)+8*(reg>>2)+4*hi; PV A-frag needs P[q][k = kk*16+hi*8+i]; the
// exchange is exactly a lane l<->l+32 swap of the cvt_pk'd dword pairs.
#define PV_STEP(SF, s16, kk) do {                                              \
    unsigned C0a = cvt_pk_bf16(SF[8*(s16)+0], SF[8*(s16)+1]);                  \
    unsigned C0b = cvt_pk_bf16(SF[8*(s16)+2], SF[8*(s16)+3]);                  \
    unsigned C1a = cvt_pk_bf16(SF[8*(s16)+4], SF[8*(s16)+5]);                  \
    unsigned C1b = cvt_pk_bf16(SF[8*(s16)+6], SF[8*(s16)+7]);                  \
    unsigned x0 = (unsigned)__shfl_xor((int)C0a, 32);                          \
    unsigned x2 = (unsigned)__shfl_xor((int)C0b, 32);                          \
    unsigned x1 = (unsigned)__shfl_xor((int)C1a, 32);                          \
    unsigned x3 = (unsigned)__shfl_xor((int)C1b, 32);                          \
    union { uint4 u; bf16x8 b; } pcv;                                          \
    pcv.u.x = hi ? x1 : C0a;                                                   \
    pcv.u.y = hi ? x3 : C0b;                                                   \
    pcv.u.z = hi ? C1a : x0;                                                   \
    pcv.u.w = hi ? C1b : x2;                                                   \
    bf16x8 vb0 = *reinterpret_cast<const bf16x8*>(&Vs[cur][KIDX(q32, (kk)*16 + hi*8)]);      \
    bf16x8 vb1 = *reinterpret_cast<const bf16x8*>(&Vs[cur][KIDX(32 + q32, (kk)*16 + hi*8)]); \
    O0 = __builtin_amdgcn_mfma_f32_32x32x16_bf16(pcv.b, vb0, O0, 0, 0, 0);     \
    O1 = __builtin_amdgcn_mfma_f32_32x32x16_bf16(pcv.b, vb1, O1, 0, 0, 0);     \
} while (0)

// ---- fused attention: 4 waves x 32q (32x32 MFMA), paired 64-row halves,
// dbuf K/V (XOR-swizzled, no Ps), in-register P transpose via shfl_xor(32) ----
__global__ __launch_bounds__(256) void k_attn(const unsigned short* __restrict__ Qb,
                                              const unsigned short* __restrict__ Kb,
                                              const unsigned short* __restrict__ Vt,
                                              float* __restrict__ Y) {
    __shared__ unsigned short Ks[2][64 * 64];   // [buf][k][d] swizzled
    __shared__ unsigned short Vs[2][64 * 64];   // [buf][d][k] swizzled
    // XCD-aware decode: 2 heads per XCD
    const int bid = blockIdx.x;
    const int x = bid & 7, i = bid >> 3;
    const int h = x * 2 + (i >> 5);
    const int bx = i & 31;
    const int t = threadIdx.x;
    const int w = t >> 6, l = t & 63;
    const int half = w >> 1, wq = w & 1;       // 4 waves = 2 tile-halves x 2 q-bands
    const int q32 = l & 31, hi = l >> 5;
    const int qbA = bx, qbB = 63 - bx;         // paired tiles: uniform PV cost
    const int qb_my = half ? qbB : qbA;
    const int vmax = qbB, pvmax = qb_my;
    const int qrel = wq * 32 + q32;            // q within the 64-row tile

    // Q B-frags (pre-scaled by QSCALE): 4 dk-chains of 16
    bf16x8 qf[4];
    {
        const unsigned short* qp = Qb + (size_t)(qb_my * 64 + qrel) * DIMC + h * 64 + hi * 8;
        qf[0] = *reinterpret_cast<const bf16x8*>(qp);
        qf[1] = *reinterpret_cast<const bf16x8*>(qp + 16);
        qf[2] = *reinterpret_cast<const bf16x8*>(qp + 32);
        qf[3] = *reinterpret_cast<const bf16x8*>(qp + 48);
    }
    float m_fr = -__builtin_inff(), l_st = 0.f;
    f32x16 O0, O1;
    #pragma unroll
    for (int j = 0; j < 16; ++j) { O0[j] = 0.f; O1[j] = 0.f; }

    // staging: 256 threads, rows r0 and r0+32, 8 elems each
    const int r0 = t >> 3, c0 = (t & 7) * 8;
    const unsigned short* gK = Kb + (size_t)r0 * DIMC + h * 64 + c0;
    const unsigned short* gV = Vt + (size_t)(h * 64 + r0) * NSEQ + c0;
    const int o_lo = KIDX(r0, c0);             // (r0+32)&7 == r0&7 -> same xor
    const int o_hi = o_lo + 32 * 64;

    // prologue: tile 0 direct to buf0; prefetch tile 1 into regs
    *reinterpret_cast<uint4*>(&Ks[0][o_lo]) = *reinterpret_cast<const uint4*>(gK);
    *reinterpret_cast<uint4*>(&Ks[0][o_hi]) = *reinterpret_cast<const uint4*>(gK + 32 * DIMC);
    *reinterpret_cast<uint4*>(&Vs[0][o_lo]) = *reinterpret_cast<const uint4*>(gV);
    *reinterpret_cast<uint4*>(&Vs[0][o_hi]) = *reinterpret_cast<const uint4*>(gV + 32 * NSEQ);
    uint4 kv0 = *reinterpret_cast<const uint4*>(gK + 64 * DIMC);
    uint4 kv1 = *reinterpret_cast<const uint4*>(gK + 96 * DIMC);
    uint4 vv0 = *reinterpret_cast<const uint4*>(gV + 64);
    uint4 vv1 = *reinterpret_cast<const uint4*>(gV + 32 * NSEQ + 64);

    for (int kt = 0; kt < 64; ++kt) {
        const int cur = kt & 1, nxt = cur ^ 1;
        __syncthreads();   // prev iter's reads done -> safe to overwrite nxt
        if (kt + 1 < 64) {
            *reinterpret_cast<uint4*>(&Ks[nxt][o_lo]) = kv0;
            *reinterpret_cast<uint4*>(&Ks[nxt][o_hi]) = kv1;
            if (kt + 1 <= vmax) {
                *reinterpret_cast<uint4*>(&Vs[nxt][o_lo]) = vv0;
                *reinterpret_cast<uint4*>(&Vs[nxt][o_hi]) = vv1;
            }
        }
        if (kt + 2 < 64) {   // prefetch kt+2 into regs (latency cover)
            kv0 = *reinterpret_cast<const uint4*>(gK + (size_t)(kt + 2) * 64 * DIMC);
            kv1 = *reinterpret_cast<const uint4*>(gK + (size_t)(kt + 2) * 64 * DIMC + 32 * DIMC);
            if (kt + 2 <= vmax) {
                vv0 = *reinterpret_cast<const uint4*>(gV + (kt + 2) * 64);
                vv1 = *reinterpret_cast<const uint4*>(gV + 32 * NSEQ + (kt + 2) * 64);
            }
        }

        // swapped QK^T (32x32): C[k][q], col q=l&31, row k=(reg&3)+8*(reg>>2)+4*hi
        f32x16 s0, s1;
        #pragma unroll
        for (int j = 0; j < 16; ++j) { s0[j] = 0.f; s1[j] = 0.f; }
        __builtin_amdgcn_s_setprio(1);
        #pragma unroll
        for (int c = 0; c < 4; ++c) {
            bf16x8 ka0 = *reinterpret_cast<const bf16x8*>(&Ks[cur][KIDX(q32,      c * 16 + hi * 8)]);
            bf16x8 ka1 = *reinterpret_cast<const bf16x8*>(&Ks[cur][KIDX(32 + q32, c * 16 + hi * 8)]);
            s0 = __builtin_amdgcn_mfma_f32_32x32x16_bf16(ka0, qf[c], s0, 0, 0, 0);
            s1 = __builtin_amdgcn_mfma_f32_32x32x16_bf16(ka1, qf[c], s1, 0, 0, 0);
        }
        __builtin_amdgcn_s_setprio(0);

        // softmax (exp2 domain). Lane holds 32 of 64 k's for q=q32; partner (l^32) rest.
        float tl = s0[0];
        #pragma unroll
        for (int j = 1; j < 16; ++j) tl = fmaxf(tl, s0[j]);
        #pragma unroll
        for (int j = 0; j < 16; ++j) tl = fmaxf(tl, s1[j]);
        const float tmax = fmaxf(tl, __shfl_xor(tl, 32));

        if (!__all(tmax <= m_fr + 8.f)) {      // defer-max: rare
            const float mnew = fmaxf(m_fr, tmax);
            const float sc = exp2f(m_fr - mnew);   // first tile: 0
            l_st *= sc;
            #pragma unroll
            for (int j = 0; j < 16; ++j) {
                const float scj = __shfl(sc, (j & 3) + 8 * (j >> 2) + 4 * hi);
                O0[j] *= scj; O1[j] *= scj;
            }
            m_fr = mnew;
        }
        float ps = 0.f;
        #pragma unroll
        for (int j = 0; j < 16; ++j) { const float p = exp2f(s0[j] - m_fr); s0[j] = p; ps += p; }
        #pragma unroll
        for (int j = 0; j < 16; ++j) { const float p = exp2f(s1[j] - m_fr); s1[j] = p; ps += p; }
        ps += __shfl_xor(ps, 32);
        l_st += ps;                             // UNMASKED full-row denominator

        if (kt <= pvmax) {
            if (kt == pvmax) {                  // diagonal: post-softmax tril mask
                #pragma unroll
                for (int j = 0; j < 16; ++j) {
                    const int kr = (j & 3) + 8 * (j >> 2) + 4 * hi;
                    if (kr > qrel) s0[j] = 0.f;
                    if (32 + kr > qrel) s1[j] = 0.f;
                }
            }
            __builtin_amdgcn_s_setprio(1);
            PV_STEP(s0, 0, 0);
            PV_STEP(s0, 1, 1);
            PV_STEP(s1, 0, 2);
            PV_STEP(s1, 1, 3);
            __builtin_amdgcn_s_setprio(0);
        }
    }

    // epilogue: O and l share frame m_fr. O row q=(j&3)+8*(j>>2)+4*hi, col d=l&31.
    const float rl = 1.0f / l_st;
    #pragma unroll
    for (int j = 0; j < 16; ++j) {
        const int row = (j & 3) + 8 * (j >> 2) + 4 * hi;
        const float rlj = __shfl(rl, row);
        const size_t yb = (size_t)(qb_my * 64 + wq * 32 + row) * DIMC + h * 64 + q32;
        Y[yb]      = O0[j] * rlj;
        Y[yb + 32] = O1[j] * rlj;
    }
}

extern "C" void kernel_launch(void* const* d_in, const int* in_sizes, int n_in,
                              void* d_out, int out_size, void* d_ws, size_t ws_size,
                              hipStream_t stream) {
    const float* content = (const float*)d_in[0];
    const float* Wq = (const float*)d_in[1];
    const float* Wk = (const float*)d_in[2];
    const float* Wv = (const float*)d_in[3];
    float* Y = (float*)d_out;
    unsigned short* ws  = (unsigned short*)d_ws;
    unsigned short* cbf = ws;
    unsigned short* wt  = cbf + (size_t)NSEQ * DIMC;
    unsigned short* qb  = wt  + (size_t)3 * DIMC * DIMC;
    unsigned short* kb  = qb  + (size_t)NSEQ * DIMC;
    unsigned short* vt  = kb  + (size_t)NSEQ * DIMC;

    hipLaunchKernelGGL(k_conv, dim3(NSEQ * DIMC / (256 * 8)), dim3(256), 0, stream, content, cbf);
    hipLaunchKernelGGL(k_wt,   dim3(32, 32, 3), dim3(32, 32), 0, stream, Wq, Wk, Wv, wt);
    hipLaunchKernelGGL(k_gemm, dim3(DIMC / 128, NSEQ / 128, 3), dim3(256), 0, stream, cbf, wt, qb, kb, vt);
    hipLaunchKernelGGL(k_attn, dim3(512), dim3(256), 0, stream, qb, kb, vt, Y);
}